// Round 3
// baseline (481.469 us; speedup 1.0000x reference)
//
#include <hip/hip_runtime.h>

// RBF layer, algebraically collapsed:
//   out[n,o] = Bo[o] - x2[n]*S1[o] + 2 * sum_d x[n,d] * M[d,o]
// where (all tiny, precomputed per launch from the constant inputs):
//   s[d]  = relu(sigma[d]);  w[k] = relu(width[k]);  Wr = relu(output_weights)
//   M[d,o]  = s[d] * sum_k center[k,d]*w[k]*Wr[1+k,o]          [256 x 128]
//   S1[o]   = sum_k w[k]*Wr[1+k,o]
//   c2[k]   = sum_d center[k,d]^2 * s[d]
//   Bo[o]   = Wr[0,o] + sum_k Wr[1+k,o] - sum_k c2[k]*w[k]*Wr[1+k,o]
//   x2[n]   = sum_d s[d]*x[n,d]^2   (fp32, computed in the main kernel)
// Main GEMM term uses bf16 MFMA 16x16x32 (abs-err contribution ~0.1 vs
// threshold ~1075; dominant x2*S1 term stays fp32).
//
// R2 lessons baked in: Mfrag lives in LDS (round-1/2 re-read 64 KB/wave-tile
// from L1/L2 = 512 MB aggregate, latency-chained in the MFMA loop); kernel is
// persistent (2 tiles/wave) to kill the one-shot ramp; 16 rows/wave keeps
// VGPR low; NO nontemporal stores (they cost +10% HBM write amplification).

typedef short  short8 __attribute__((ext_vector_type(8)));
typedef __bf16 bf16x8 __attribute__((ext_vector_type(8)));
typedef float  f32x4  __attribute__((ext_vector_type(4)));

#define N_ 131072
#define D_ 256
#define K_ 256
#define O_ 128

__device__ __forceinline__ unsigned short f2bf_bits(float f) {
  unsigned u = __builtin_bit_cast(unsigned, f);
  u += 0x7fffu + ((u >> 16) & 1u);   // round-to-nearest-even
  return (unsigned short)(u >> 16);
}

__device__ __forceinline__ float relu(float v) { return v > 0.f ? v : 0.f; }

// ---- Precompute kernel: 65 blocks x 256 threads ---------------------------
// Blocks 0..63: one (ks,ot) B-fragment tile of M each (32 d x 16 o), with
// ww[k][oc]=relu(w)*relu(Wr) and cen[k][dc] staged in LDS so the 256-deep
// k-loop is pure LDS. Block 64: c2 -> LDS, then Bo[o], S1[o].
__global__ __launch_bounds__(256) void rbf_pre(
    const float* __restrict__ center, const float* __restrict__ sigma,
    const float* __restrict__ width,  const float* __restrict__ W,
    short* __restrict__ Mfrag, float* __restrict__ Bo, float* __restrict__ S1)
{
  const int tid = threadIdx.x;
  if (blockIdx.x < 64) {
    const int ot = blockIdx.x & 7;
    const int ks = blockIdx.x >> 3;
    __shared__ float ww[K_][16];   // 16 KB
    __shared__ float cen[K_][32];  // 32 KB
#pragma unroll
    for (int i = 0; i < 16; ++i) {
      const int k  = i * 16 + (tid >> 4);
      const int oc = tid & 15;
      ww[k][oc] = relu(width[k]) * relu(W[(1 + k) * O_ + ot * 16 + oc]);
    }
#pragma unroll
    for (int i = 0; i < 32; ++i) {
      const int k  = i * 8 + (tid >> 5);
      const int dc = tid & 31;
      cen[k][dc] = center[k * D_ + ks * 32 + dc];
    }
    __syncthreads();
    const int j   = tid & 7;
    const int lf  = tid >> 3;              // 0..31 == MFMA lane field
    const int oc  = lf & 15;
    const int dc1 = (lf >> 4) * 8 + j;     // 0..15
    float a1 = 0.f, a2 = 0.f;
#pragma unroll 8
    for (int k = 0; k < K_; ++k) {
      const float w = ww[k][oc];
      a1 = fmaf(cen[k][dc1],      w, a1);
      a2 = fmaf(cen[k][dc1 + 16], w, a2);
    }
    const int e1 = blockIdx.x * 512 + tid;
    const int d1 = ks * 32 + dc1;
    Mfrag[e1]       = (short)f2bf_bits(a1 * relu(sigma[d1]));
    Mfrag[e1 + 256] = (short)f2bf_bits(a2 * relu(sigma[d1 + 16]));
  } else {
    __shared__ float c2s[K_];
    {
      const int k = tid;
      float acc = 0.f;
      for (int d = 0; d < D_; ++d) {
        const float c = center[k * D_ + d];
        acc = fmaf(c * c, relu(sigma[d]), acc);
      }
      c2s[k] = acc;
    }
    __syncthreads();
    if (tid < O_) {
      const int o = tid;
      float s1 = 0.f, sum = 0.f, c2w = 0.f;
      for (int k = 0; k < K_; ++k) {
        const float w  = relu(width[k]);
        const float wr = relu(W[(1 + k) * O_ + o]);
        s1  = fmaf(w, wr, s1);
        sum += wr;
        c2w = fmaf(c2s[k] * w, wr, c2w);
      }
      Bo[o] = relu(W[o]) + sum - c2w;
      S1[o] = s1;
    }
  }
}

// ---- Main kernel: 512 blocks x 512 threads (8 waves), persistent ----------
// Mfrag (64 KiB) staged to LDS once per block; each wave processes 2 tiles of
// 16 rows. Exactly 2 blocks/CU co-resident (LDS-capped) = 16 waves/CU.
__global__ __launch_bounds__(512, 3) void rbf_main(
    const float* __restrict__ x, const float* __restrict__ sigma,
    const short* __restrict__ Mfrag, const float* __restrict__ Bo,
    const float* __restrict__ S1, float* __restrict__ out)
{
  __shared__ short8 Blds[4096];                 // 64 KiB, B-fragment layout
  const int tid = threadIdx.x;
  {
    const short8* Mf8 = (const short8*)Mfrag;
#pragma unroll
    for (int i = 0; i < 8; ++i)                 // lane-contiguous, coalesced
      Blds[i * 512 + tid] = Mf8[i * 512 + tid];
  }

  const int lane = tid & 63;
  const int wv   = tid >> 6;                    // 0..7
  const int m    = lane & 15;                   // A row / C col within tile
  const int q    = lane >> 4;                   // quad
  const int gw   = blockIdx.x * 8 + wv;         // 0..4095

  __syncthreads();

  for (int it = 0; it < 2; ++it) {
    const long tile    = (long)gw + (long)it * 4096;   // 0..8191
    const long rowBase = tile * 16;
    const float* xr = x + (rowBase + m) * D_ + q * 8;

    // Burst-issue the 16 KB A-tile load (16 dwordx4 per lane pair-pattern).
    f32x4 raw[16];
#pragma unroll
    for (int ks = 0; ks < 8; ++ks) {
      raw[2 * ks]     = *(const f32x4*)(xr + ks * 32);
      raw[2 * ks + 1] = *(const f32x4*)(xr + ks * 32 + 4);
    }

    // Convert to bf16 A-fragments; accumulate fp32 x2 along the way.
    const float* sp = sigma + q * 8;
    bf16x8 a[8];
    float x2 = 0.f;
#pragma unroll
    for (int ks = 0; ks < 8; ++ks) {
      float sv[8], v[8];
      *(f32x4*)(sv)     = *(const f32x4*)(sp + ks * 32);      // L1-hot (1 KB)
      *(f32x4*)(sv + 4) = *(const f32x4*)(sp + ks * 32 + 4);
      *(f32x4*)(v)      = raw[2 * ks];
      *(f32x4*)(v + 4)  = raw[2 * ks + 1];
      short8 ab;
#pragma unroll
      for (int jj = 0; jj < 8; ++jj) {
        const float s = relu(sv[jj]);
        x2 = fmaf(s * v[jj], v[jj], x2);
        ab[jj] = (short)f2bf_bits(v[jj]);
      }
      a[ks] = __builtin_bit_cast(bf16x8, ab);
    }
    // Reduce x2 across the 4 lanes holding the same row.
    x2 += __shfl_xor(x2, 16);
    x2 += __shfl_xor(x2, 32);

#pragma unroll
    for (int ot = 0; ot < 8; ++ot) {
      f32x4 acc = {0.f, 0.f, 0.f, 0.f};
#pragma unroll
      for (int ks = 0; ks < 8; ++ks) {
        const bf16x8 bb =
            __builtin_bit_cast(bf16x8, Blds[(ks * 8 + ot) * 64 + lane]);
        acc = __builtin_amdgcn_mfma_f32_16x16x32_bf16(a[ks], bb, acc, 0, 0, 0);
      }
      const int   o  = ot * 16 + m;        // C/D: col = lane&15
      const float bo = Bo[o];              // L1-hot
      const float s1 = S1[o];
      float* op = out + rowBase * O_ + o;
#pragma unroll
      for (int r = 0; r < 4; ++r) {
        const int rr = q * 4 + r;          // C/D: row = (lane>>4)*4 + reg
        const float x2r = __shfl(x2, rr);  // broadcast from lane rr (<16)
        op[(long)rr * O_] = fmaf(2.f, acc[r], fmaf(-x2r, s1, bo));
      }
    }
  }
}

extern "C" void kernel_launch(void* const* d_in, const int* in_sizes, int n_in,
                              void* d_out, int out_size, void* d_ws, size_t ws_size,
                              hipStream_t stream) {
  (void)in_sizes; (void)n_in; (void)out_size; (void)ws_size;
  const float* x      = (const float*)d_in[0];
  const float* center = (const float*)d_in[1];
  const float* sigma  = (const float*)d_in[2];
  const float* width  = (const float*)d_in[3];
  const float* W      = (const float*)d_in[4];
  float* out = (float*)d_out;

  short* Mfrag = (short*)d_ws;                       // 64 KiB
  float* Bo    = (float*)((char*)d_ws + 65536);      // 512 B
  float* S1    = (float*)((char*)d_ws + 66048);      // 512 B

  hipLaunchKernelGGL(rbf_pre, dim3(65), dim3(256), 0, stream,
                     center, sigma, width, W, Mfrag, Bo, S1);
  hipLaunchKernelGGL(rbf_main, dim3(512), dim3(512), 0, stream,
                     x, sigma, Mfrag, Bo, S1, out);
}

// Round 4
// 250.636 us; speedup vs baseline: 1.9210x; 1.9210x over previous
//
#include <hip/hip_runtime.h>

// RBF layer, algebraically collapsed:
//   out[n,o] = Bo[o] - x2[n]*S1[o] + 2 * sum_d x[n,d] * M[d,o]
// where (all tiny, precomputed per launch from the constant inputs):
//   s[d]  = relu(sigma[d]);  w[k] = relu(width[k]);  Wr = relu(output_weights)
//   M[d,o]  = s[d] * sum_k center[k,d]*w[k]*Wr[1+k,o]          [256 x 128]
//   S1[o]   = sum_k w[k]*Wr[1+k,o]
//   c2[k]   = sum_d center[k,d]^2 * s[d]
//   Bo[o]   = Wr[0,o] + sum_k Wr[1+k,o] - sum_k c2[k]*w[k]*Wr[1+k,o]
//   x2[n]   = sum_d s[d]*x[n,d]^2   (fp32, computed in the main kernel)
// Main GEMM term uses bf16 MFMA 16x16x32 (abs-err ~0.1 vs threshold ~1075).
//
// Evidence log:
//  R2: nontemporal stores -> +10% WRITE_SIZE (write amplification). Plain stores.
//  R3: __launch_bounds__(512,3) forced VGPR cap ~170 -> raw[]/a[] spilled to
//      scratch (+290 MB FETCH, +300 MB WRITE, 340 us). LDS staging itself was
//      correct (absmax unchanged, 0 bank conflicts).
//  R4: same structure, (512,2) cap -> no spill; one-shot grid.

typedef short  short8 __attribute__((ext_vector_type(8)));
typedef __bf16 bf16x8 __attribute__((ext_vector_type(8)));
typedef float  f32x4  __attribute__((ext_vector_type(4)));

#define N_ 131072
#define D_ 256
#define K_ 256
#define O_ 128

__device__ __forceinline__ unsigned short f2bf_bits(float f) {
  unsigned u = __builtin_bit_cast(unsigned, f);
  u += 0x7fffu + ((u >> 16) & 1u);   // round-to-nearest-even
  return (unsigned short)(u >> 16);
}

__device__ __forceinline__ float relu(float v) { return v > 0.f ? v : 0.f; }

// ---- Precompute kernel: 65 blocks x 256 threads ---------------------------
// Blocks 0..63: one (ks,ot) B-fragment tile of M each (32 d x 16 o), with
// ww[k][oc]=relu(w)*relu(Wr) and cen[k][dc] staged in LDS so the 256-deep
// k-loop is pure LDS. Block 64: c2 -> LDS, then Bo[o], S1[o].
__global__ __launch_bounds__(256) void rbf_pre(
    const float* __restrict__ center, const float* __restrict__ sigma,
    const float* __restrict__ width,  const float* __restrict__ W,
    short* __restrict__ Mfrag, float* __restrict__ Bo, float* __restrict__ S1)
{
  const int tid = threadIdx.x;
  if (blockIdx.x < 64) {
    const int ot = blockIdx.x & 7;
    const int ks = blockIdx.x >> 3;
    __shared__ float ww[K_][16];   // 16 KB
    __shared__ float cen[K_][32];  // 32 KB
#pragma unroll
    for (int i = 0; i < 16; ++i) {
      const int k  = i * 16 + (tid >> 4);
      const int oc = tid & 15;
      ww[k][oc] = relu(width[k]) * relu(W[(1 + k) * O_ + ot * 16 + oc]);
    }
#pragma unroll
    for (int i = 0; i < 32; ++i) {
      const int k  = i * 8 + (tid >> 5);
      const int dc = tid & 31;
      cen[k][dc] = center[k * D_ + ks * 32 + dc];
    }
    __syncthreads();
    const int j   = tid & 7;
    const int lf  = tid >> 3;              // 0..31 == MFMA lane field
    const int oc  = lf & 15;
    const int dc1 = (lf >> 4) * 8 + j;     // 0..15
    float a1 = 0.f, a2 = 0.f;
#pragma unroll 8
    for (int k = 0; k < K_; ++k) {
      const float w = ww[k][oc];
      a1 = fmaf(cen[k][dc1],      w, a1);
      a2 = fmaf(cen[k][dc1 + 16], w, a2);
    }
    const int e1 = blockIdx.x * 512 + tid;
    const int d1 = ks * 32 + dc1;
    Mfrag[e1]       = (short)f2bf_bits(a1 * relu(sigma[d1]));
    Mfrag[e1 + 256] = (short)f2bf_bits(a2 * relu(sigma[d1 + 16]));
  } else {
    __shared__ float c2s[K_];
    {
      // 4 independent chains, f32x4 loads: latency-tolerant.
      const f32x4* cr = (const f32x4*)(center + tid * D_);
      const f32x4* sr = (const f32x4*)sigma;
      f32x4 acc = {0.f, 0.f, 0.f, 0.f};
#pragma unroll 8
      for (int d4 = 0; d4 < D_ / 4; ++d4) {
        const f32x4 c = cr[d4];
        const f32x4 s = sr[d4];
#pragma unroll
        for (int e = 0; e < 4; ++e) acc[e] = fmaf(c[e] * c[e], relu(s[e]), acc[e]);
      }
      c2s[tid] = (acc[0] + acc[1]) + (acc[2] + acc[3]);
    }
    __syncthreads();
    if (tid < O_) {
      const int o = tid;
      float s1 = 0.f, sum = 0.f, c2w = 0.f;
#pragma unroll 4
      for (int k = 0; k < K_; ++k) {
        const float w  = relu(width[k]);
        const float wr = relu(W[(1 + k) * O_ + o]);
        s1  = fmaf(w, wr, s1);
        sum += wr;
        c2w = fmaf(c2s[k] * w, wr, c2w);
      }
      Bo[o] = relu(W[o]) + sum - c2w;
      S1[o] = s1;
    }
  }
}

// ---- Main kernel: 1024 blocks x 512 threads (8 waves), one tile/wave ------
// Mfrag (64 KiB) staged to LDS once per block (staging loads issued BEFORE the
// x burst so the pre-barrier vmcnt drain overlaps both); MFMA loop is pure
// LDS+registers. (512,2): VGPR cap ~256 -> no spills (R3 lesson).
__global__ __launch_bounds__(512, 2) void rbf_main(
    const float* __restrict__ x, const float* __restrict__ sigma,
    const short* __restrict__ Mfrag, const float* __restrict__ Bo,
    const float* __restrict__ S1, float* __restrict__ out)
{
  __shared__ short8 Blds[4096];                 // 64 KiB, B-fragment layout
  const int tid  = threadIdx.x;
  const int lane = tid & 63;
  const int wv   = tid >> 6;                    // 0..7
  const int m    = lane & 15;                   // A row / C col within tile
  const int q    = lane >> 4;                   // quad
  const long rowBase = ((long)blockIdx.x * 8 + wv) * 16;

  // Stage Mfrag -> LDS (8 x dwordx4 per thread, lane-contiguous; L2-hot).
  short8 stg[8];
  const short8* Mf8 = (const short8*)Mfrag;
#pragma unroll
  for (int i = 0; i < 8; ++i) stg[i] = Mf8[i * 512 + tid];

  // Burst-issue the 16 KB x A-tile load (16 dwordx4 per thread).
  const float* xr = x + (rowBase + m) * D_ + q * 8;
  f32x4 raw[16];
#pragma unroll
  for (int ks = 0; ks < 8; ++ks) {
    raw[2 * ks]     = *(const f32x4*)(xr + ks * 32);
    raw[2 * ks + 1] = *(const f32x4*)(xr + ks * 32 + 4);
  }

#pragma unroll
  for (int i = 0; i < 8; ++i) Blds[i * 512 + tid] = stg[i];

  // Convert to bf16 A-fragments; accumulate fp32 x2 along the way.
  const float* sp = sigma + q * 8;
  bf16x8 a[8];
  float x2 = 0.f;
#pragma unroll
  for (int ks = 0; ks < 8; ++ks) {
    float sv[8], v[8];
    *(f32x4*)(sv)     = *(const f32x4*)(sp + ks * 32);      // L1-hot (1 KB)
    *(f32x4*)(sv + 4) = *(const f32x4*)(sp + ks * 32 + 4);
    *(f32x4*)(v)      = raw[2 * ks];
    *(f32x4*)(v + 4)  = raw[2 * ks + 1];
    short8 ab;
#pragma unroll
    for (int jj = 0; jj < 8; ++jj) {
      const float s = relu(sv[jj]);
      x2 = fmaf(s * v[jj], v[jj], x2);
      ab[jj] = (short)f2bf_bits(v[jj]);
    }
    a[ks] = __builtin_bit_cast(bf16x8, ab);
  }
  // Reduce x2 across the 4 lanes holding the same row.
  x2 += __shfl_xor(x2, 16);
  x2 += __shfl_xor(x2, 32);

  __syncthreads();                              // Blds ready

#pragma unroll
  for (int ot = 0; ot < 8; ++ot) {
    f32x4 acc = {0.f, 0.f, 0.f, 0.f};
#pragma unroll
    for (int ks = 0; ks < 8; ++ks) {
      const bf16x8 bb =
          __builtin_bit_cast(bf16x8, Blds[(ks * 8 + ot) * 64 + lane]);
      acc = __builtin_amdgcn_mfma_f32_16x16x32_bf16(a[ks], bb, acc, 0, 0, 0);
    }
    const int   o  = ot * 16 + m;        // C/D: col = lane&15
    const float bo = Bo[o];              // L1-hot (512 B)
    const float s1 = S1[o];
    float* op = out + rowBase * O_ + o;
#pragma unroll
    for (int r = 0; r < 4; ++r) {
      const int rr = q * 4 + r;          // C/D: row = (lane>>4)*4 + reg
      const float x2r = __shfl(x2, rr);  // broadcast from lane rr (<16)
      op[(long)rr * O_] = fmaf(2.f, acc[r], fmaf(-x2r, s1, bo));
    }
  }
}

extern "C" void kernel_launch(void* const* d_in, const int* in_sizes, int n_in,
                              void* d_out, int out_size, void* d_ws, size_t ws_size,
                              hipStream_t stream) {
  (void)in_sizes; (void)n_in; (void)out_size; (void)ws_size;
  const float* x      = (const float*)d_in[0];
  const float* center = (const float*)d_in[1];
  const float* sigma  = (const float*)d_in[2];
  const float* width  = (const float*)d_in[3];
  const float* W      = (const float*)d_in[4];
  float* out = (float*)d_out;

  short* Mfrag = (short*)d_ws;                       // 64 KiB
  float* Bo    = (float*)((char*)d_ws + 65536);      // 512 B
  float* S1    = (float*)((char*)d_ws + 66048);      // 512 B

  hipLaunchKernelGGL(rbf_pre, dim3(65), dim3(256), 0, stream,
                     center, sigma, width, W, Mfrag, Bo, S1);
  hipLaunchKernelGGL(rbf_main, dim3(1024), dim3(512), 0, stream,
                     x, sigma, Mfrag, Bo, S1, out);
}